// Round 7
// baseline (606.065 us; speedup 1.0000x reference)
//
#include <hip/hip_runtime.h>

// IGCN forward, CSR formulation, round 7.
//  - ONE CSR (from adj edges) serves feat-SpMM (+bias, degF=degA+1) and all
//    adj-SpMMs. CSR built via two-level bucketing with LDS-staged COALESCED
//    appends (no random 4B global scatter anywhere):
//      Phase A: 256 buckets of 512 rows; blocks stage entries in LDS bins,
//               flush 32-entry (128B) aligned chunks to per-bucket regions.
//      Phase B: one block per bucket; LDS histogram+scan over 512 rows;
//               scatter confined to the bucket's 50KB colA window.
//  - Scaled-state trick: buffers hold y~ = rsD[row]*y[row]; adj SpMM inner
//    loop is a pure gather-sum; gathered rows un-scale by sqrt(deg).
//  - SpMM: wave = 4 edge-slots x 16 dim-lanes, unroll 2.

constexpr int kNU = 60000;
constexpr int kNI = 40000;
constexpr int kN  = 100000;
constexpr int kB  = 4096;

constexpr int NBK    = 256;     // buckets
constexpr int RPB    = 512;     // rows per bucket (256*512 >= 100000)
constexpr int BINCAP = 56;      // LDS entries per bin  (58KB total LDS)
constexpr int BCAP   = 16384;   // global entries per bucket (max ~13k + slack)

// ---------------- Phase A: bin pairs into buckets (coalesced appends) -------
__global__ void binA(const int* __restrict__ uArr, const int* __restrict__ iArr,
                     int nP, int* __restrict__ gTail, int* __restrict__ bucketMem) {
  __shared__ int binCnt[NBK];
  __shared__ int binBuf[NBK][BINCAP];
  int tid = threadIdx.x, lane = tid & 63, w = tid >> 6;
  for (int i = tid; i < NBK; i += 256) binCnt[i] = 0;
  __syncthreads();
  int per = (nP + gridDim.x - 1) / gridDim.x;
  int p0 = blockIdx.x * per, p1 = min(nP, p0 + per);
  for (int q0 = p0; q0 < p1; q0 += 256) {
    int p = q0 + tid;
    if (p < p1) {
      int u = uArr[p], v = iArr[p];
      int b1 = u >> 9, e1 = ((u & 511) << 17) | v;
      int ix = atomicAdd(&binCnt[b1], 1); binBuf[b1][ix] = e1;
      int b2 = v >> 9, e2 = ((v & 511) << 17) | u;
      int iy = atomicAdd(&binCnt[b2], 1); binBuf[b2][iy] = e2;
    }
    __syncthreads();
    // wave w owns bins [w*64, w*64+64): flush multiples of 32 (128B chunks)
    int myCnt = binCnt[w * 64 + lane];
    unsigned long long m = __ballot(myCnt >= 32);
    while (m) {
      int brel = __ffsll((long long)m) - 1; m &= m - 1;
      int b = w * 64 + brel;
      int c = __shfl(myCnt, brel, 64);
      int nf = c & ~31;
      int tail = 0;
      if (lane == 0) tail = atomicAdd(&gTail[b], nf);
      tail = __shfl(tail, 0, 64);
      int* dst = bucketMem + b * BCAP + tail;
      for (int k = lane; k < nf; k += 64) dst[k] = binBuf[b][k];
      int rem = c - nf;
      int t = (lane < rem) ? binBuf[b][nf + lane] : 0;
      if (lane < rem) binBuf[b][lane] = t;
      if (lane == 0) binCnt[b] = rem;
    }
    __syncthreads();
  }
  // final flush (remainders, partial chunks ok)
  int myCnt = binCnt[w * 64 + lane];
  unsigned long long m = __ballot(myCnt > 0);
  while (m) {
    int brel = __ffsll((long long)m) - 1; m &= m - 1;
    int b = w * 64 + brel;
    int c = __shfl(myCnt, brel, 64);
    int tail = 0;
    if (lane == 0) tail = atomicAdd(&gTail[b], c);
    tail = __shfl(tail, 0, 64);
    for (int k = lane; k < c; k += 64) bucketMem[b * BCAP + tail + k] = binBuf[b][k];
  }
}

// ---------------- bucket prefix (tiny) --------------------------------------
__global__ void scan_buckets(const int* __restrict__ gTail, int* __restrict__ bucketBase,
                             int* __restrict__ rowStart) {
  if (threadIdx.x == 0 && blockIdx.x == 0) {
    int run = 0;
    for (int i = 0; i < NBK; ++i) { bucketBase[i] = run; run += gTail[i]; }
    bucketBase[NBK] = run;
    rowStart[kN] = run;   // == neA
  }
}

// ---------------- Phase B: per-bucket CSR (count/scan/scatter in window) ----
__global__ void buildB(const int* __restrict__ bucketMem, const int* __restrict__ gTail,
                       const int* __restrict__ bucketBase, int* __restrict__ colA,
                       int* __restrict__ rowStart, float* __restrict__ rsDg,
                       float* __restrict__ sqrtD) {
  int b = blockIdx.x;
  int n = gTail[b], base = bucketBase[b];
  int tid = threadIdx.x, lane = tid & 63, w = tid >> 6;
  __shared__ int cnt[RPB];
  __shared__ int wsum[4];
  for (int i = tid; i < RPB; i += 256) cnt[i] = 0;
  __syncthreads();
  const int* src = bucketMem + b * BCAP;
  for (int i = tid; i < n; i += 256) atomicAdd(&cnt[src[i] >> 17], 1);
  __syncthreads();
  // block scan over 512 counters (2 per thread)
  int v0 = cnt[2 * tid], v1 = cnt[2 * tid + 1], ts = v0 + v1;
  int x = ts;
  #pragma unroll
  for (int off = 1; off < 64; off <<= 1) {
    int y = __shfl_up(x, off, 64);
    if (lane >= off) x += y;
  }
  if (lane == 63) wsum[w] = x;
  __syncthreads();
  int wpre = 0;
  for (int k = 0; k < w; ++k) wpre += wsum[k];
  int pre = wpre + x - ts;     // exclusive prefix for this thread's 2 rows
  int grow = b * RPB + 2 * tid;
  if (grow < kN) {
    rowStart[grow] = base + pre;
    rsDg[grow]  = v0 > 0 ? rsqrtf((float)v0) : 1.f;
    sqrtD[grow] = v0 > 0 ? sqrtf((float)v0) : 1.f;
  }
  if (grow + 1 < kN) {
    rowStart[grow + 1] = base + pre + v0;
    rsDg[grow + 1]  = v1 > 0 ? rsqrtf((float)v1) : 1.f;
    sqrtD[grow + 1] = v1 > 0 ? sqrtf((float)v1) : 1.f;
  }
  __syncthreads();
  cnt[2 * tid] = pre;
  cnt[2 * tid + 1] = pre + v0;
  __syncthreads();
  for (int i = tid; i < n; i += 256) {
    int e = src[i];
    int p = atomicAdd(&cnt[e >> 17], 1);
    colA[base + p] = e & 0x1FFFF;
  }
}

// ---------------- SpMM: wave = 4 edge-slots x 16 dim-lanes, unroll 2 --------
// feat: out~[row] = rsDg[row] * (sum emb[c] + emb[bias]) / (deg+1)
__global__ void spmm_feat_half(const int* __restrict__ rs, const int* __restrict__ cols,
                               const float4* __restrict__ emb4, float4* __restrict__ out4,
                               const float* __restrict__ rsDg,
                               int row0, int nrows, int biasIdx) {
  int r = blockIdx.x * 4 + (threadIdx.x >> 6);
  if (r >= nrows) return;
  int row = row0 + r;
  int lane = threadIdx.x & 63, g = lane >> 4, q = lane & 15;
  int s = rs[row], e = rs[row + 1];
  float4 a = {0.f, 0.f, 0.f, 0.f}, b = {0.f, 0.f, 0.f, 0.f};
  int j = s + g;
  for (; j + 4 < e; j += 8) {
    int c0 = cols[j], c1 = cols[j + 4];
    float4 v0 = emb4[(long)c0 * 16 + q];
    float4 v1 = emb4[(long)c1 * 16 + q];
    a.x += v0.x; a.y += v0.y; a.z += v0.z; a.w += v0.w;
    b.x += v1.x; b.y += v1.y; b.z += v1.z; b.w += v1.w;
  }
  if (j < e) {
    int c = cols[j];
    float4 v = emb4[(long)c * 16 + q];
    a.x += v.x; a.y += v.y; a.z += v.z; a.w += v.w;
  }
  a.x += b.x; a.y += b.y; a.z += b.z; a.w += b.w;
  #pragma unroll
  for (int m = 16; m <= 32; m <<= 1) {
    a.x += __shfl_xor(a.x, m, 64);
    a.y += __shfl_xor(a.y, m, 64);
    a.z += __shfl_xor(a.z, m, 64);
    a.w += __shfl_xor(a.w, m, 64);
  }
  if (g == 0) {
    float4 bv = emb4[(long)biasIdx * 16 + q];
    float sc = rsDg[row] / (float)(e - s + 1);
    a.x = (a.x + bv.x) * sc; a.y = (a.y + bv.y) * sc;
    a.z = (a.z + bv.z) * sc; a.w = (a.w + bv.w) * sc;
    out4[(long)r * 16 + q] = a;
  }
}

// adj: out~[row] = (1/deg[row]) * sum in~[c]
__global__ void spmm_adj_half(const int* __restrict__ rs, const int* __restrict__ cols,
                              const float* __restrict__ rsDg, const float4* __restrict__ in4,
                              float4* __restrict__ out4, int row0, int nrows, int colOff) {
  int r = blockIdx.x * 4 + (threadIdx.x >> 6);
  if (r >= nrows) return;
  int row = row0 + r;
  int lane = threadIdx.x & 63, g = lane >> 4, q = lane & 15;
  int s = rs[row], e = rs[row + 1];
  float4 a = {0.f, 0.f, 0.f, 0.f}, b = {0.f, 0.f, 0.f, 0.f};
  int j = s + g;
  for (; j + 4 < e; j += 8) {
    int c0 = cols[j], c1 = cols[j + 4];
    float4 v0 = in4[(long)(c0 - colOff) * 16 + q];
    float4 v1 = in4[(long)(c1 - colOff) * 16 + q];
    a.x += v0.x; a.y += v0.y; a.z += v0.z; a.w += v0.w;
    b.x += v1.x; b.y += v1.y; b.z += v1.z; b.w += v1.w;
  }
  if (j < e) {
    int c = cols[j];
    float4 v = in4[(long)(c - colOff) * 16 + q];
    a.x += v.x; a.y += v.y; a.z += v.z; a.w += v.w;
  }
  a.x += b.x; a.y += b.y; a.z += b.z; a.w += b.w;
  #pragma unroll
  for (int m = 16; m <= 32; m <<= 1) {
    a.x += __shfl_xor(a.x, m, 64);
    a.y += __shfl_xor(a.y, m, 64);
    a.z += __shfl_xor(a.z, m, 64);
    a.w += __shfl_xor(a.w, m, 64);
  }
  if (g == 0) {
    float w2 = rsDg[row]; w2 = w2 * w2;   // = 1/deg (deg>0)
    a.x *= w2; a.y *= w2; a.z *= w2; a.w *= w2;
    out4[(long)r * 16 + q] = a;
  }
}

// ---------------- gathered-row accumulation (un-scale by sqrt(deg)) ---------
__global__ void acc_gather(const float4* __restrict__ bufU, const float4* __restrict__ bufI,
                           const float* __restrict__ sqrtD,
                           const int* __restrict__ users, const int* __restrict__ pos,
                           const int* __restrict__ neg, float4* __restrict__ out, int add) {
  int g = blockIdx.x * blockDim.x + threadIdx.x;
  if (g >= 3 * kB * 16) return;
  int slot = g >> 4, q = g & 15;
  int which = slot >> 12, b = slot & (kB - 1);
  int node = which == 0 ? users[b] : (which == 1 ? pos[b] + kNU : neg[b] + kNU);
  float4 v = (node < kNU) ? bufU[(long)node * 16 + q] : bufI[(long)(node - kNU) * 16 + q];
  float sq = sqrtD[node];
  v.x *= sq; v.y *= sq; v.z *= sq; v.w *= sq;
  if (add) { float4 o = out[g]; v.x += o.x; v.y += o.y; v.z += o.z; v.w += o.w; }
  out[g] = v;
}

// layer 3 restricted to gathered rows + /4 + per-row L2 partial
__global__ void layer3_fin(const int* __restrict__ rs, const int* __restrict__ cols,
                           const float* __restrict__ rsDg,
                           const float4* __restrict__ bufU, const float4* __restrict__ bufI,
                           const int* __restrict__ users, const int* __restrict__ pos,
                           const int* __restrict__ neg,
                           float4* __restrict__ out, float* __restrict__ l2part) {
  int slot = blockIdx.x * 4 + (threadIdx.x >> 6);
  if (slot >= 3 * kB) return;
  int lane = threadIdx.x & 63, g = lane >> 4, q = lane & 15;
  int which = slot >> 12, b = slot & (kB - 1);
  int node = which == 0 ? users[b] : (which == 1 ? pos[b] + kNU : neg[b] + kNU);
  const float4* in; int coff;
  if (node < kNU) { in = bufI; coff = kNU; } else { in = bufU; coff = 0; }
  int s = rs[node], e = rs[node + 1];
  float4 a = {0.f, 0.f, 0.f, 0.f}, bb = {0.f, 0.f, 0.f, 0.f};
  int j = s + g;
  for (; j + 4 < e; j += 8) {
    int c0 = cols[j], c1 = cols[j + 4];
    float4 v0 = in[(long)(c0 - coff) * 16 + q];
    float4 v1 = in[(long)(c1 - coff) * 16 + q];
    a.x += v0.x; a.y += v0.y; a.z += v0.z; a.w += v0.w;
    bb.x += v1.x; bb.y += v1.y; bb.z += v1.z; bb.w += v1.w;
  }
  if (j < e) {
    int c = cols[j];
    float4 v = in[(long)(c - coff) * 16 + q];
    a.x += v.x; a.y += v.y; a.z += v.z; a.w += v.w;
  }
  a.x += bb.x; a.y += bb.y; a.z += bb.z; a.w += bb.w;
  #pragma unroll
  for (int m = 16; m <= 32; m <<= 1) {
    a.x += __shfl_xor(a.x, m, 64);
    a.y += __shfl_xor(a.y, m, 64);
    a.z += __shfl_xor(a.z, m, 64);
    a.w += __shfl_xor(a.w, m, 64);
  }
  float sr = rsDg[node];
  float4 o = out[(long)slot * 16 + q];
  float rx = (o.x + a.x * sr) * 0.25f;
  float ry = (o.y + a.y * sr) * 0.25f;
  float rz = (o.z + a.z * sr) * 0.25f;
  float rw = (o.w + a.w * sr) * 0.25f;
  if (g == 0) { float4 rv = {rx, ry, rz, rw}; out[(long)slot * 16 + q] = rv; }
  float t = rx * rx + ry * ry + rz * rz + rw * rw;
  #pragma unroll
  for (int m = 1; m <= 8; m <<= 1) t += __shfl_xor(t, m, 64);
  if (lane == 0) l2part[slot] = t;
}

__global__ void l2_final(const float* __restrict__ l2part, float* __restrict__ outl2) {
  int b = blockIdx.x * blockDim.x + threadIdx.x;
  if (b < kB) outl2[b] = l2part[b] + l2part[kB + b] + l2part[2 * kB + b];
}

extern "C" void kernel_launch(void* const* d_in, const int* in_sizes, int n_in,
                              void* d_out, int out_size, void* d_ws, size_t ws_size,
                              hipStream_t stream) {
  const float* emb  = (const float*)d_in[0];
  const int*   arow = (const int*)d_in[3];
  const int*   users= (const int*)d_in[5];
  const int*   pos  = (const int*)d_in[6];
  const int*   neg  = (const int*)d_in[7];
  const int neA = in_sizes[3];              // 2,000,000
  const int nP  = neA / 2;                  // 1,000,000 pairs
  const int* uArr = arow;                   // values in [0, 60000)
  const int* iArr = arow + nP;              // values in [60000, 100000)

  char* ws = (char*)d_ws;
  int*   gTail      = (int*)(ws + 0);          //   1,024
  int*   bucketBase = (int*)(ws + 1024);       //   1,028 (pad to 2112)
  int*   rowStart   = (int*)(ws + 2112);       // 400,004 (pad to 402176)
  float* rsDg       = (float*)(ws + 402176);   // 400,000
  float* sqrtD      = (float*)(ws + 802176);   // 400,000
  float* l2part     = (float*)(ws + 1202176);  //  49,152
  int*   colA       = (int*)(ws + 1251328);    // 8,000,000
  int*   bucketMem  = (int*)(ws + 9251328);    // 16,777,216 (dead after buildB)
  float* bufU       = (float*)(ws + 9251328);  // 15,360,000 (aliases bucketMem)
  float* bufI0      = (float*)(ws + 24611328); // 10,240,000
  float* bufI1      = (float*)(ws + 34851328); // 10,240,000 -> end 45,091,328

  float* out = (float*)d_out;

  hipMemsetAsync(gTail, 0, 1024, stream);
  binA<<<64, 256, 0, stream>>>(uArr, iArr, nP, gTail, bucketMem);
  scan_buckets<<<1, 64, 0, stream>>>(gTail, bucketBase, rowStart);
  buildB<<<NBK, 256, 0, stream>>>(bucketMem, gTail, bucketBase, colA, rowStart,
                                  rsDg, sqrtD);

  // feature SpMM -> scaled state y~0
  spmm_feat_half<<<(kNU + 3) / 4, 256, 0, stream>>>(rowStart, colA, (const float4*)emb,
                                                    (float4*)bufU, rsDg, 0, kNU, 100000);
  spmm_feat_half<<<(kNI + 3) / 4, 256, 0, stream>>>(rowStart, colA, (const float4*)emb,
                                                    (float4*)bufI0, rsDg, kNU, kNI, 100001);
  acc_gather<<<(3 * kB * 16 + 255) / 256, 256, 0, stream>>>((const float4*)bufU,
      (const float4*)bufI0, sqrtD, users, pos, neg, (float4*)out, 0);

  // layer 1: items from U, then users from I0 (bufU in place)
  spmm_adj_half<<<(kNI + 3) / 4, 256, 0, stream>>>(rowStart, colA, rsDg, (const float4*)bufU,
                                                   (float4*)bufI1, kNU, kNI, 0);
  spmm_adj_half<<<(kNU + 3) / 4, 256, 0, stream>>>(rowStart, colA, rsDg, (const float4*)bufI0,
                                                   (float4*)bufU, 0, kNU, kNU);
  acc_gather<<<(3 * kB * 16 + 255) / 256, 256, 0, stream>>>((const float4*)bufU,
      (const float4*)bufI1, sqrtD, users, pos, neg, (float4*)out, 1);

  // layer 2
  spmm_adj_half<<<(kNI + 3) / 4, 256, 0, stream>>>(rowStart, colA, rsDg, (const float4*)bufU,
                                                   (float4*)bufI0, kNU, kNI, 0);
  spmm_adj_half<<<(kNU + 3) / 4, 256, 0, stream>>>(rowStart, colA, rsDg, (const float4*)bufI1,
                                                   (float4*)bufU, 0, kNU, kNU);
  acc_gather<<<(3 * kB * 16 + 255) / 256, 256, 0, stream>>>((const float4*)bufU,
      (const float4*)bufI0, sqrtD, users, pos, neg, (float4*)out, 1);

  // layer 3 restricted + epilogue
  layer3_fin<<<(3 * kB + 3) / 4, 256, 0, stream>>>(rowStart, colA, rsDg, (const float4*)bufU,
                                                   (const float4*)bufI0, users, pos, neg,
                                                   (float4*)out, l2part);
  l2_final<<<(kB + 255) / 256, 256, 0, stream>>>(l2part, out + 3 * kB * 64);
}

// Round 8
// 364.574 us; speedup vs baseline: 1.6624x; 1.6624x over previous
//
#include <hip/hip_runtime.h>
#include <hip/hip_fp16.h>

// IGCN forward, round 8: round-4 CSR build (best measured) + fp16 scaled-state
// intermediates + merged full-node SpMM dispatches (no in-place hazard).
//  - ONE CSR (from adj edges) serves feat-SpMM (+bias, degF=degA+1) and all
//    adj-SpMMs; ranged build = round 4 verbatim.
//  - Scaled state y~ = rsD[row]*y[row] stored as fp16 (halves gather bytes);
//    adj inner loop is a pure gather-sum; gathered rows un-scale by sqrt(deg).
//  - adj SpMM: wave = 8 edge-slots x 8 dim-lanes, 16B fp16 row-chunk per lane.

constexpr int kNU = 60000;
constexpr int kNI = 40000;
constexpr int kN  = 100000;
constexpr int kB  = 4096;
constexpr int kNRange = 8, kRangeSz = 12500;
constexpr int kNChunk = 256;

struct alignas(16) H8 { __half2 h[4]; };   // 8 halfs = 16B
struct alignas(8)  H4 { __half2 lo, hi; }; // 4 halfs = 8B

// ---------------- CSR build (round-4 ranged version, verbatim) --------------
__global__ void count_deg_ranged(const int4* __restrict__ u4, const int4* __restrict__ i4,
                                 int nV, int* __restrict__ deg) {
  int range = blockIdx.x & (kNRange - 1);
  int chunk = blockIdx.x >> 3;
  int lo = range * kRangeSz, hi = lo + kRangeSz;
  int chunkLen = (nV + kNChunk - 1) / kNChunk;
  int p0 = chunk * chunkLen, p1 = min(nV, p0 + chunkLen);
  for (int p = p0 + (int)threadIdx.x; p < p1; p += 256) {
    int4 uu = u4[p], ii = i4[p];
    if (uu.x >= lo && uu.x < hi) atomicAdd(&deg[uu.x], 1);
    if (uu.y >= lo && uu.y < hi) atomicAdd(&deg[uu.y], 1);
    if (uu.z >= lo && uu.z < hi) atomicAdd(&deg[uu.z], 1);
    if (uu.w >= lo && uu.w < hi) atomicAdd(&deg[uu.w], 1);
    if (ii.x >= lo && ii.x < hi) atomicAdd(&deg[ii.x], 1);
    if (ii.y >= lo && ii.y < hi) atomicAdd(&deg[ii.y], 1);
    if (ii.z >= lo && ii.z < hi) atomicAdd(&deg[ii.z], 1);
    if (ii.w >= lo && ii.w < hi) atomicAdd(&deg[ii.w], 1);
  }
}

__global__ void scatter_ranged(const int4* __restrict__ u4, const int4* __restrict__ i4,
                               int nV, int* __restrict__ cur, int* __restrict__ colsOut) {
  int range = blockIdx.x & (kNRange - 1);
  int chunk = blockIdx.x >> 3;
  int lo = range * kRangeSz, hi = lo + kRangeSz;
  int chunkLen = (nV + kNChunk - 1) / kNChunk;
  int p0 = chunk * chunkLen, p1 = min(nV, p0 + chunkLen);
  for (int p = p0 + (int)threadIdx.x; p < p1; p += 256) {
    int4 uu = u4[p], ii = i4[p];
    if (uu.x >= lo && uu.x < hi) colsOut[atomicAdd(&cur[uu.x], 1)] = ii.x;
    if (ii.x >= lo && ii.x < hi) colsOut[atomicAdd(&cur[ii.x], 1)] = uu.x;
    if (uu.y >= lo && uu.y < hi) colsOut[atomicAdd(&cur[uu.y], 1)] = ii.y;
    if (ii.y >= lo && ii.y < hi) colsOut[atomicAdd(&cur[ii.y], 1)] = uu.y;
    if (uu.z >= lo && uu.z < hi) colsOut[atomicAdd(&cur[uu.z], 1)] = ii.z;
    if (ii.z >= lo && ii.z < hi) colsOut[atomicAdd(&cur[ii.z], 1)] = uu.z;
    if (uu.w >= lo && uu.w < hi) colsOut[atomicAdd(&cur[uu.w], 1)] = ii.w;
    if (ii.w >= lo && ii.w < hi) colsOut[atomicAdd(&cur[ii.w], 1)] = uu.w;
  }
}

// ---------------- scan ----------------
constexpr int SCAN_T = 256, SCAN_E = 8, SCAN_CH = SCAN_T * SCAN_E;  // 2048

__global__ void scan_p1(const int* __restrict__ in, int n, int* __restrict__ bsum) {
  __shared__ int lds[SCAN_T];
  int t = threadIdx.x;
  int base = blockIdx.x * SCAN_CH + t * SCAN_E;
  int s = 0;
  #pragma unroll
  for (int k = 0; k < SCAN_E; ++k) { int i = base + k; if (i < n) s += in[i]; }
  lds[t] = s; __syncthreads();
  for (int off = SCAN_T / 2; off; off >>= 1) {
    if (t < off) lds[t] += lds[t + off];
    __syncthreads();
  }
  if (t == 0) bsum[blockIdx.x] = lds[0];
}

__global__ void scan_p2(int* bsum, int nb) {
  if (threadIdx.x == 0 && blockIdx.x == 0) {
    int run = 0;
    for (int i = 0; i < nb; ++i) { int v = bsum[i]; bsum[i] = run; run += v; }
  }
}

__global__ void scan_p3(const int* __restrict__ in, int n, int ntot,
                        const int* __restrict__ bsum,
                        int* __restrict__ out, int* __restrict__ cur) {
  __shared__ int lds[SCAN_T];
  int t = threadIdx.x;
  int base = blockIdx.x * SCAN_CH + t * SCAN_E;
  int v[SCAN_E]; int s = 0;
  #pragma unroll
  for (int k = 0; k < SCAN_E; ++k) { int i = base + k; v[k] = (i < n) ? in[i] : 0; s += v[k]; }
  lds[t] = s; __syncthreads();
  for (int off = 1; off < SCAN_T; off <<= 1) {
    int x = (t >= off) ? lds[t - off] : 0;
    __syncthreads();
    lds[t] += x;
    __syncthreads();
  }
  int pre = lds[t] - s + bsum[blockIdx.x];
  #pragma unroll
  for (int k = 0; k < SCAN_E; ++k) {
    int i = base + k;
    if (i < n) { out[i] = pre; cur[i] = pre; pre += v[k]; }
  }
  if (blockIdx.x == 0 && t == 0) out[n] = ntot;
}

__global__ void make_rsd(const int* __restrict__ deg, float* __restrict__ rsDg, int n) {
  int i = blockIdx.x * blockDim.x + threadIdx.x;
  if (i < n) { int d = deg[i]; rsDg[i] = d > 0 ? rsqrtf((float)d) : 1.f; }
}

// ---------------- feat SpMM, all nodes: f32 emb gather -> fp16 y~0 ----------
// wave = 4 edge-slots x 16 dim-lanes (float4), unroll 2.
__global__ void spmm_feat_all(const int* __restrict__ rs, const int* __restrict__ cols,
                              const float4* __restrict__ emb4, const float* __restrict__ rsDg,
                              H4* __restrict__ hU, H4* __restrict__ hI) {
  int row = blockIdx.x * 4 + (threadIdx.x >> 6);
  if (row >= kN) return;
  int lane = threadIdx.x & 63, g = lane >> 4, q = lane & 15;
  int s = rs[row], e = rs[row + 1];
  float4 a = {0.f, 0.f, 0.f, 0.f}, b = {0.f, 0.f, 0.f, 0.f};
  int j = s + g;
  for (; j + 4 < e; j += 8) {
    int c0 = cols[j], c1 = cols[j + 4];
    float4 v0 = emb4[(long)c0 * 16 + q];
    float4 v1 = emb4[(long)c1 * 16 + q];
    a.x += v0.x; a.y += v0.y; a.z += v0.z; a.w += v0.w;
    b.x += v1.x; b.y += v1.y; b.z += v1.z; b.w += v1.w;
  }
  if (j < e) {
    int c = cols[j];
    float4 v = emb4[(long)c * 16 + q];
    a.x += v.x; a.y += v.y; a.z += v.z; a.w += v.w;
  }
  a.x += b.x; a.y += b.y; a.z += b.z; a.w += b.w;
  #pragma unroll
  for (int m = 16; m <= 32; m <<= 1) {
    a.x += __shfl_xor(a.x, m, 64);
    a.y += __shfl_xor(a.y, m, 64);
    a.z += __shfl_xor(a.z, m, 64);
    a.w += __shfl_xor(a.w, m, 64);
  }
  if (g == 0) {
    int biasIdx = (row < kNU) ? 100000 : 100001;
    float4 bv = emb4[(long)biasIdx * 16 + q];
    float sc = rsDg[row] / (float)(e - s + 1);
    float2 lo = {(a.x + bv.x) * sc, (a.y + bv.y) * sc};
    float2 hi = {(a.z + bv.z) * sc, (a.w + bv.w) * sc};
    H4 o; o.lo = __float22half2_rn(lo); o.hi = __float22half2_rn(hi);
    H4* dst = (row < kNU) ? (hU + (long)row * 16) : (hI + (long)(row - kNU) * 16);
    dst[q] = o;
  }
}

// ---------------- adj SpMM, all nodes: fp16 gather-sum -> fp16 --------------
// wave = 8 edge-slots x 8 dim-lanes (16B H8 per lane), unroll 2.
__global__ void spmm_adj_all(const int* __restrict__ rs, const int* __restrict__ cols,
                             const float* __restrict__ rsDg,
                             const H8* __restrict__ inU, const H8* __restrict__ inI,
                             H8* __restrict__ outU, H8* __restrict__ outI) {
  int row = blockIdx.x * 4 + (threadIdx.x >> 6);
  if (row >= kN) return;
  int lane = threadIdx.x & 63, g = lane >> 3, q = lane & 7;
  const H8* src; int coff;
  if (row < kNU) { src = inI; coff = kNU; } else { src = inU; coff = 0; }
  int s = rs[row], e = rs[row + 1];
  float a[8];
  #pragma unroll
  for (int k = 0; k < 8; ++k) a[k] = 0.f;
  int j = s + g;
  for (; j + 8 < e; j += 16) {
    int c0 = cols[j], c1 = cols[j + 8];
    H8 v0 = src[(long)(c0 - coff) * 8 + q];
    H8 v1 = src[(long)(c1 - coff) * 8 + q];
    #pragma unroll
    for (int k = 0; k < 4; ++k) {
      float2 f0 = __half22float2(v0.h[k]);
      float2 f1 = __half22float2(v1.h[k]);
      a[2 * k]     += f0.x + f1.x;
      a[2 * k + 1] += f0.y + f1.y;
    }
  }
  if (j < e) {
    int c = cols[j];
    H8 v = src[(long)(c - coff) * 8 + q];
    #pragma unroll
    for (int k = 0; k < 4; ++k) {
      float2 f = __half22float2(v.h[k]);
      a[2 * k] += f.x; a[2 * k + 1] += f.y;
    }
  }
  #pragma unroll
  for (int m = 8; m <= 32; m <<= 1) {
    #pragma unroll
    for (int k = 0; k < 8; ++k) a[k] += __shfl_xor(a[k], m, 64);
  }
  if (g == 0) {
    float w = rsDg[row]; w = w * w;   // = 1/deg (deg>0); empty row -> 0 sum
    H8 o;
    #pragma unroll
    for (int k = 0; k < 4; ++k) {
      float2 f = {a[2 * k] * w, a[2 * k + 1] * w};
      o.h[k] = __float22half2_rn(f);
    }
    H8* dst = (row < kNU) ? (outU + (long)row * 8) : (outI + (long)(row - kNU) * 8);
    dst[q] = o;
  }
}

// ---------------- gathered-row accumulation (un-scale by sqrt(deg)) ---------
__global__ void acc_gather_h(const H8* __restrict__ hU, const H8* __restrict__ hI,
                             const int* __restrict__ deg,
                             const int* __restrict__ users, const int* __restrict__ pos,
                             const int* __restrict__ neg, float4* __restrict__ out, int add) {
  int gI = blockIdx.x * blockDim.x + threadIdx.x;
  if (gI >= 3 * kB * 8) return;
  int slot = gI >> 3, q = gI & 7;
  int which = slot >> 12, b = slot & (kB - 1);
  int node = which == 0 ? users[b] : (which == 1 ? pos[b] + kNU : neg[b] + kNU);
  H8 v = (node < kNU) ? hU[(long)node * 8 + q] : hI[(long)(node - kNU) * 8 + q];
  float sq = sqrtf((float)max(deg[node], 1));
  float4 r0, r1;
  float2 f0 = __half22float2(v.h[0]), f1 = __half22float2(v.h[1]);
  float2 f2 = __half22float2(v.h[2]), f3 = __half22float2(v.h[3]);
  r0 = {f0.x * sq, f0.y * sq, f1.x * sq, f1.y * sq};
  r1 = {f2.x * sq, f2.y * sq, f3.x * sq, f3.y * sq};
  long o0 = (long)slot * 16 + q * 2;
  if (add) {
    float4 a0 = out[o0], a1 = out[o0 + 1];
    r0.x += a0.x; r0.y += a0.y; r0.z += a0.z; r0.w += a0.w;
    r1.x += a1.x; r1.y += a1.y; r1.z += a1.z; r1.w += a1.w;
  }
  out[o0] = r0; out[o0 + 1] = r1;
}

// ---------------- layer 3 restricted + /4 + per-row L2 ----------------------
__global__ void layer3_fin(const int* __restrict__ rs, const int* __restrict__ cols,
                           const float* __restrict__ rsDg,
                           const H8* __restrict__ hU, const H8* __restrict__ hI,
                           const int* __restrict__ users, const int* __restrict__ pos,
                           const int* __restrict__ neg,
                           float4* __restrict__ out, float* __restrict__ l2part) {
  int slot = blockIdx.x * 4 + (threadIdx.x >> 6);
  if (slot >= 3 * kB) return;
  int lane = threadIdx.x & 63, g = lane >> 3, q = lane & 7;
  int which = slot >> 12, b = slot & (kB - 1);
  int node = which == 0 ? users[b] : (which == 1 ? pos[b] + kNU : neg[b] + kNU);
  const H8* src; int coff;
  if (node < kNU) { src = hI; coff = kNU; } else { src = hU; coff = 0; }
  int s = rs[node], e = rs[node + 1];
  float a[8];
  #pragma unroll
  for (int k = 0; k < 8; ++k) a[k] = 0.f;
  int j = s + g;
  for (; j + 8 < e; j += 16) {
    int c0 = cols[j], c1 = cols[j + 8];
    H8 v0 = src[(long)(c0 - coff) * 8 + q];
    H8 v1 = src[(long)(c1 - coff) * 8 + q];
    #pragma unroll
    for (int k = 0; k < 4; ++k) {
      float2 f0 = __half22float2(v0.h[k]);
      float2 f1 = __half22float2(v1.h[k]);
      a[2 * k]     += f0.x + f1.x;
      a[2 * k + 1] += f0.y + f1.y;
    }
  }
  if (j < e) {
    int c = cols[j];
    H8 v = src[(long)(c - coff) * 8 + q];
    #pragma unroll
    for (int k = 0; k < 4; ++k) {
      float2 f = __half22float2(v.h[k]);
      a[2 * k] += f.x; a[2 * k + 1] += f.y;
    }
  }
  #pragma unroll
  for (int m = 8; m <= 32; m <<= 1) {
    #pragma unroll
    for (int k = 0; k < 8; ++k) a[k] += __shfl_xor(a[k], m, 64);
  }
  float t = 0.f;
  if (g == 0) {
    float sr = rsDg[node];   // y3 = rsDg * sum(in~)
    long o0 = (long)slot * 16 + q * 2;
    float4 a0 = out[o0], a1 = out[o0 + 1];
    float4 r0 = {(a0.x + a[0] * sr) * 0.25f, (a0.y + a[1] * sr) * 0.25f,
                 (a0.z + a[2] * sr) * 0.25f, (a0.w + a[3] * sr) * 0.25f};
    float4 r1 = {(a1.x + a[4] * sr) * 0.25f, (a1.y + a[5] * sr) * 0.25f,
                 (a1.z + a[6] * sr) * 0.25f, (a1.w + a[7] * sr) * 0.25f};
    out[o0] = r0; out[o0 + 1] = r1;
    t = r0.x * r0.x + r0.y * r0.y + r0.z * r0.z + r0.w * r0.w
      + r1.x * r1.x + r1.y * r1.y + r1.z * r1.z + r1.w * r1.w;
  }
  #pragma unroll
  for (int m = 1; m <= 4; m <<= 1) t += __shfl_xor(t, m, 64);
  if (lane == 0) l2part[slot] = t;
}

__global__ void l2_final(const float* __restrict__ l2part, float* __restrict__ outl2) {
  int b = blockIdx.x * blockDim.x + threadIdx.x;
  if (b < kB) outl2[b] = l2part[b] + l2part[kB + b] + l2part[2 * kB + b];
}

extern "C" void kernel_launch(void* const* d_in, const int* in_sizes, int n_in,
                              void* d_out, int out_size, void* d_ws, size_t ws_size,
                              hipStream_t stream) {
  const float* emb  = (const float*)d_in[0];
  const int*   arow = (const int*)d_in[3];
  const int*   users= (const int*)d_in[5];
  const int*   pos  = (const int*)d_in[6];
  const int*   neg  = (const int*)d_in[7];
  const int neA = in_sizes[3];              // 2,000,000
  const int nP  = neA / 2;                  // 1,000,000 pairs
  const int nV  = nP / 4;
  const int4* u4 = (const int4*)arow;
  const int4* i4 = (const int4*)(arow + nP);

  char* ws = (char*)d_ws;
  int*    degA   = (int*)(ws + 0);           // 400,000
  int*    rsArr  = (int*)(ws + 400000);      // 400,004 (pad to 400128)
  int*    cur    = (int*)(ws + 800128);      // 400,000
  float*  rsDg   = (float*)(ws + 1200128);   // 400,000
  float*  l2part = (float*)(ws + 1600128);   // 49,152
  int*    bsum   = (int*)(ws + 1649280);     // 1,024
  int*    colA   = (int*)(ws + 1650304);     // 8,000,000
  __half* hU0    = (__half*)(ws + 9650304);  // 7,680,000
  __half* hU1    = (__half*)(ws + 17330304); // 7,680,000
  __half* hI0    = (__half*)(ws + 25010304); // 5,120,000
  __half* hI1    = (__half*)(ws + 30130304); // 5,120,000 -> end 35,250,304

  float* out = (float*)d_out;
  const int NB = (kN + SCAN_CH - 1) / SCAN_CH;  // 49

  hipMemsetAsync(degA, 0, 400000, stream);
  count_deg_ranged<<<kNRange * kNChunk, 256, 0, stream>>>(u4, i4, nV, degA);
  scan_p1<<<NB, SCAN_T, 0, stream>>>(degA, kN, bsum);
  scan_p2<<<1, 64, 0, stream>>>(bsum, NB);
  scan_p3<<<NB, SCAN_T, 0, stream>>>(degA, kN, neA, bsum, rsArr, cur);
  make_rsd<<<(kN + 255) / 256, 256, 0, stream>>>(degA, rsDg, kN);
  scatter_ranged<<<kNRange * kNChunk, 256, 0, stream>>>(u4, i4, nV, cur, colA);

  const int GN = (kN + 3) / 4;   // 25000 blocks, 4 rows each

  // feature SpMM -> fp16 scaled state y~0
  spmm_feat_all<<<GN, 256, 0, stream>>>(rsArr, colA, (const float4*)emb, rsDg,
                                        (H4*)hU0, (H4*)hI0);
  acc_gather_h<<<(3 * kB * 8 + 255) / 256, 256, 0, stream>>>((const H8*)hU0, (const H8*)hI0,
      degA, users, pos, neg, (float4*)out, 0);

  // layer 1: (hU0,hI0) -> (hU1,hI1)
  spmm_adj_all<<<GN, 256, 0, stream>>>(rsArr, colA, rsDg, (const H8*)hU0, (const H8*)hI0,
                                       (H8*)hU1, (H8*)hI1);
  acc_gather_h<<<(3 * kB * 8 + 255) / 256, 256, 0, stream>>>((const H8*)hU1, (const H8*)hI1,
      degA, users, pos, neg, (float4*)out, 1);

  // layer 2: (hU1,hI1) -> (hU0,hI0)
  spmm_adj_all<<<GN, 256, 0, stream>>>(rsArr, colA, rsDg, (const H8*)hU1, (const H8*)hI1,
                                       (H8*)hU0, (H8*)hI0);
  acc_gather_h<<<(3 * kB * 8 + 255) / 256, 256, 0, stream>>>((const H8*)hU0, (const H8*)hI0,
      degA, users, pos, neg, (float4*)out, 1);

  // layer 3 restricted + epilogue (reads layer-2 state)
  layer3_fin<<<(3 * kB + 3) / 4, 256, 0, stream>>>(rsArr, colA, rsDg, (const H8*)hU0,
                                                   (const H8*)hI0, users, pos, neg,
                                                   (float4*)out, l2part);
  l2_final<<<(kB + 255) / 256, 256, 0, stream>>>(l2part, out + 3 * kB * 64);
}